// Round 8
// baseline (622.310 us; speedup 1.0000x reference)
//
#include <hip/hip_runtime.h>
#include <hip/hip_bf16.h>
#include <hip/hip_cooperative_groups.h>

namespace cg = cooperative_groups;

// ---------------------------------------------------------------------------
// Sparse conv backbone, bf16 MFMA, round 8.
// Cooperative persistent mega-kernel (grid.sync between stages) with
// occupancy-queried grid size + full fallback to the r6 multi-kernel path
// if the cooperative launch is rejected (r7 failed with zero output =
// unchecked hipLaunchCooperativeKernel validation failure, most likely
// grid 768 > maxActiveBlocks at the compiler's actual VGPR count).
// Math identical to r6 (ref-passing at absmax 0.109):
//   sparse_conv: out[j] = sum_k fpad[in_map[k][j]] @ W[k] (identity scatter)
//   MFMA 16x16x32 bf16; split-K over 4 waves (taps padded to 28, zero wts);
//   4-wave LDS reduce; BN stats in conv epilogue; bn_relu fused into the
//   consumer conv's gather.
// ---------------------------------------------------------------------------

typedef float f4 __attribute__((ext_vector_type(4)));
typedef short short8 __attribute__((ext_vector_type(8)));
typedef short short4v __attribute__((ext_vector_type(4)));

#define BN_EPS 1e-5f

static inline int ceil_div(int a, int b) { return (a + b - 1) / b; }
__device__ static inline int dceil(int a, int b) { return (a + b - 1) / b; }

static __device__ inline float btof(short s) {
    unsigned u = ((unsigned)(unsigned short)s) << 16;
    float f;
    __builtin_memcpy(&f, &u, 4);
    return f;
}
static __device__ inline short ftob(float f) {
    __hip_bfloat16 h = __float2bfloat16(f);
    short s;
    __builtin_memcpy(&s, &h, 2);
    return s;
}

struct Seg {
    const float* W;
    long long begin, end;
    int K, CIN, COUT;
};

struct MegaArgs {
    Seg s[10];
    const float* geo;
    const float* col;
    __hip_bfloat16* x0;
    int n_vox;
    float* stats;                  // 8 slots x [4][2][64] = 4096 floats
    __hip_bfloat16* pads[5];
    int padn[5];
    long long wf_total;
    long long pro_total;
    __hip_bfloat16* Wf;
    __hip_bfloat16 *A, *B, *Cb, *D, *E, *Fb;
    float* outf;
    const int *m1, *m2, *m3, *m4;
    const float *g_e1, *b_e1, *g_e2, *b_e2;
    long long off_stem, off_c2;
    long long off_e1[4], off_e2[4];
    int nc2, nc4;
};

// ---------------- BN coefficient helper ----------------
template <int C>
__device__ inline void bn_coef(const float* st, const float* g, const float* b,
                               int c, int n, float& sc, float& sh) {
    float rn = 1.f / (float)n;
    float sum = st[c] + st[2 * C + c] + st[4 * C + c] + st[6 * C + c];
    float sq  = st[C + c] + st[3 * C + c] + st[5 * C + c] + st[7 * C + c];
    float mu = sum * rn;
    float inv = rsqrtf(sq * rn - mu * mu + BN_EPS);
    sc = inv * g[c];
    sh = b[c] - mu * sc;
}

// ---------------- stage: pack weights + build x0 + zero stats/pads ----------
__device__ void do_prologue(const MegaArgs& pa) {
    for (long long e = (long long)blockIdx.x * 256 + threadIdx.x; e < pa.pro_total;
         e += (long long)gridDim.x * 256) {
        if (e < pa.wf_total) {
            int si = 0;
#pragma unroll
            for (int i = 0; i < 10; ++i)
                if (e >= pa.s[i].end) si = i + 1;
            const Seg sg = pa.s[si];
            long long r = e - sg.begin;
            int j = (int)(r & 7);
            int lane = (int)((r >> 3) & 63);
            long long rest = r >> 9;
            int NT = sg.COUT >> 4;
            int ntile = (int)(rest % NT);
            int chunk = (int)(rest / NT);
            int kd = chunk * 32 + ((lane >> 4) << 3) + j;
            int koff = kd / sg.CIN;
            int ci = kd % sg.CIN;
            int n = ntile * 16 + (lane & 15);
            float v = (koff < sg.K) ? sg.W[((size_t)koff * sg.CIN + ci) * sg.COUT + n] : 0.f;
            pa.Wf[e] = __float2bfloat16(v);
            continue;
        }
        long long r = e - pa.wf_total;
        if (r < pa.n_vox) {
            int row = (int)r;
            pa.x0[row * 4 + 0] = __float2bfloat16(pa.geo[row]);
            pa.x0[row * 4 + 1] = __float2bfloat16(pa.col[row * 3 + 0]);
            pa.x0[row * 4 + 2] = __float2bfloat16(pa.col[row * 3 + 1]);
            pa.x0[row * 4 + 3] = __float2bfloat16(pa.col[row * 3 + 2]);
            continue;
        }
        r -= pa.n_vox;
        if (r < 4096) {
            pa.stats[r] = 0.f;
            continue;
        }
        r -= 4096;
#pragma unroll
        for (int i = 0; i < 5; ++i) {
            if (r < pa.padn[i]) {
                pa.pads[i][r] = __float2bfloat16(0.f);
                r = -1;
                break;
            }
            r -= pa.padn[i];
        }
    }
}

// ---------------- stage: stem conv (CIN=4, COUT=32, K=125->128, relu) -------
__device__ void stage_stem(const MegaArgs& a) {
    const int t = threadIdx.x, w = t >> 6, lane = t & 63;
    const int quad = lane >> 4, ml = lane & 15;
    const int ntile = w & 1, mgroup = w >> 1;
    const int n_out = a.nc2, n_in = a.n_vox;
    const __hip_bfloat16* feat = a.x0;
    const __hip_bfloat16* Wf = a.Wf + a.off_stem;
    const int* in_map = a.m1;
    __hip_bfloat16* out = a.A;
    const int ntiles = dceil(n_out, 64);
    for (int tile = blockIdx.x; tile < ntiles; tile += gridDim.x) {
        const int mb = tile * 64 + mgroup * 32;
        const int m0 = mb + ml, m1 = mb + 16 + ml;
        const bool v0 = m0 < n_out, v1 = m1 < n_out;
        f4 acc0 = {0.f, 0.f, 0.f, 0.f};
        f4 acc1 = {0.f, 0.f, 0.f, 0.f};
#pragma unroll 2
        for (int chunk = 0; chunk < 16; ++chunk) {
            int k0 = chunk * 8 + quad * 2;
            int k1 = k0 + 1;
            int k0c = (k0 < 125) ? k0 : 0;   // weights zero for k>=125
            int k1c = (k1 < 125) ? k1 : 0;
            short8 b = *(const short8*)(Wf + ((size_t)(chunk * 2 + ntile) * 64 + lane) * 8);
            int ia = v0 ? in_map[(size_t)k0c * n_out + m0] : n_in;
            int ib = v0 ? in_map[(size_t)k1c * n_out + m0] : n_in;
            int ic = v1 ? in_map[(size_t)k0c * n_out + m1] : n_in;
            int id = v1 ? in_map[(size_t)k1c * n_out + m1] : n_in;
            short4v p0 = *(const short4v*)(feat + (size_t)ia * 4);
            short4v p1 = *(const short4v*)(feat + (size_t)ib * 4);
            short4v p2 = *(const short4v*)(feat + (size_t)ic * 4);
            short4v p3 = *(const short4v*)(feat + (size_t)id * 4);
            short8 a0, a1;
            a0[0] = p0[0]; a0[1] = p0[1]; a0[2] = p0[2]; a0[3] = p0[3];
            a0[4] = p1[0]; a0[5] = p1[1]; a0[6] = p1[2]; a0[7] = p1[3];
            a1[0] = p2[0]; a1[1] = p2[1]; a1[2] = p2[2]; a1[3] = p2[3];
            a1[4] = p3[0]; a1[5] = p3[1]; a1[6] = p3[2]; a1[7] = p3[3];
            acc0 = __builtin_amdgcn_mfma_f32_16x16x32_bf16(a0, b, acc0, 0, 0, 0);
            acc1 = __builtin_amdgcn_mfma_f32_16x16x32_bf16(a1, b, acc1, 0, 0, 0);
        }
        const int col = ntile * 16 + ml;
#pragma unroll
        for (int i = 0; i < 4; ++i) {
            int r0 = mb + quad * 4 + i;
            if (r0 < n_out)
                out[(size_t)r0 * 32 + col] = __float2bfloat16(fmaxf(acc0[i], 0.f));
            int r1 = mb + 16 + quad * 4 + i;
            if (r1 < n_out)
                out[(size_t)r1 * 32 + col] = __float2bfloat16(fmaxf(acc1[i], 0.f));
        }
    }
}

// ---------------- stage: split-K MFMA conv ----------------
template <int CIN, int COUT, int MT, int K, bool BNF>
__device__ void stage_conv(const __hip_bfloat16* __restrict__ feat,
                           const __hip_bfloat16* __restrict__ Wf,
                           const int* __restrict__ in_map,
                           __hip_bfloat16* __restrict__ out,
                           float* __restrict__ stats,
                           const float* __restrict__ in_stats,
                           const float* __restrict__ in_g,
                           const float* __restrict__ in_b,
                           int n_out, int n_in,
                           float* red, float* sred, float* ibn) {
    constexpr int NT = COUT / 16;
    constexpr int H = CIN / 32;
    constexpr int R = MT * 16;
    constexpr int KPW = (K + 3) / 4;
    const int t = threadIdx.x, w = t >> 6, lane = t & 63;
    const int quad = lane >> 4, ml = lane & 15;

    if constexpr (BNF) {
        if (t < CIN) {
            float sc, sh;
            bn_coef<CIN>(in_stats, in_g, in_b, t, n_in, sc, sh);
            ibn[t] = sc;
            ibn[CIN + t] = sh;
        }
        __syncthreads();
    }
    float scr[H][8], shr[H][8];
    if constexpr (BNF) {
#pragma unroll
        for (int h = 0; h < H; ++h)
#pragma unroll
            for (int j = 0; j < 8; ++j) {
                int ch = h * 32 + quad * 8 + j;
                scr[h][j] = ibn[ch];
                shr[h][j] = ibn[CIN + ch];
            }
    }

    const int ntiles = dceil(n_out, R);
    for (int tile = blockIdx.x; tile < ntiles; tile += gridDim.x) {
        const int mb = tile * R;
        f4 acc[MT * NT];
#pragma unroll
        for (int i = 0; i < MT * NT; ++i) acc[i] = (f4){0.f, 0.f, 0.f, 0.f};

#pragma unroll
        for (int kk = 0; kk < KPW; ++kk) {
            const int k = kk * 4 + w;
            const int krow = (k < K) ? k : 0;     // branchless; weights zero k>=K
            const int* mk = in_map + (size_t)krow * n_out;
            int idx[MT];
#pragma unroll
            for (int mi = 0; mi < MT; ++mi) {
                int m = mb + mi * 16 + ml;
                idx[mi] = (m < n_out) ? mk[m] : n_in;
            }
            short8 bfrag[H * NT];
#pragma unroll
            for (int h = 0; h < H; ++h)
#pragma unroll
                for (int nt = 0; nt < NT; ++nt)
                    bfrag[h * NT + nt] = *(const short8*)(
                        Wf + (((size_t)(k * H + h) * NT + nt) * 64 + lane) * 8);
#pragma unroll
            for (int mi = 0; mi < MT; ++mi) {
                const __hip_bfloat16* fp = feat + (size_t)idx[mi] * CIN + quad * 8;
                const bool sent = (idx[mi] == n_in);
#pragma unroll
                for (int h = 0; h < H; ++h) {
                    short8 av = *(const short8*)(fp + h * 32);
                    if constexpr (BNF) {
#pragma unroll
                        for (int j = 0; j < 8; ++j) {
                            float f = btof(av[j]) * scr[h][j] + shr[h][j];
                            f = fmaxf(f, 0.f);
                            av[j] = sent ? (short)0 : ftob(f);
                        }
                    }
#pragma unroll
                    for (int nt = 0; nt < NT; ++nt)
                        acc[mi * NT + nt] = __builtin_amdgcn_mfma_f32_16x16x32_bf16(
                            av, bfrag[h * NT + nt], acc[mi * NT + nt], 0, 0, 0);
                }
            }
        }

#pragma unroll
        for (int mi = 0; mi < MT; ++mi)
#pragma unroll
            for (int nt = 0; nt < NT; ++nt)
#pragma unroll
                for (int i = 0; i < 4; ++i)
                    red[((size_t)w * R + mi * 16 + quad * 4 + i) * COUT + nt * 16 + ml] =
                        acc[mi * NT + nt][i];
        __syncthreads();

        constexpr int E = (R * COUT) / 256;
        constexpr int RSTEP = 256 / COUT;
        const int col = t % COUT;
        const int rg = t / COUT;
        float s = 0.f, s2 = 0.f;
#pragma unroll
        for (int i = 0; i < E; ++i) {
            int r = rg + i * RSTEP;
            float v = red[(0 * R + r) * COUT + col] + red[(1 * R + r) * COUT + col] +
                      red[(2 * R + r) * COUT + col] + red[(3 * R + r) * COUT + col];
            s += v;
            s2 += v * v;
            int grow = mb + r;
            if (grow < n_out) out[(size_t)grow * COUT + col] = __float2bfloat16(v);
        }

        if (stats) {
            sred[t] = s;
            sred[256 + t] = s2;
            __syncthreads();
            if (t < 2 * COUT) {
                int c = t % COUT;
                int which = t / COUT;   // 0 = sum, 1 = sumsq
                float v = 0.f;
#pragma unroll
                for (int j = 0; j < RSTEP; ++j) v += sred[which * 256 + j * COUT + c];
                atomicAdd(&stats[((tile & 3) * 2 + which) * COUT + c], v);
            }
        }
        __syncthreads();   // protect red/sred reuse by next tile
    }
}

// ---------------- stage: BN residual apply ----------------
template <int C, bool F32OUT>
__device__ void stage_bnres(const __hip_bfloat16* __restrict__ y,
                            const __hip_bfloat16* __restrict__ res,
                            const float* __restrict__ st,
                            const float* __restrict__ g,
                            const float* __restrict__ b,
                            void* outp, int n, float* ibn) {
    const int t = threadIdx.x;
    if (t < C) {
        float sc, sh;
        bn_coef<C>(st, g, b, t, n, sc, sh);
        ibn[t] = sc;
        ibn[C + t] = sh;
    }
    __syncthreads();
    long long tot = (long long)n * (C / 8);
    for (long long i = (long long)blockIdx.x * 256 + t; i < tot;
         i += (long long)gridDim.x * 256) {
        int c0 = (int)(i % (C / 8)) * 8;
        short8 v = *(const short8*)(y + i * 8);
        short8 r = *(const short8*)(res + i * 8);
        if constexpr (F32OUT) {
            float* out = (float*)outp;
            f4 o0, o1;
#pragma unroll
            for (int j = 0; j < 8; ++j) {
                float f = btof(v[j]) * ibn[c0 + j] + ibn[C + c0 + j] + btof(r[j]);
                f = fmaxf(f, 0.f);
                if (j < 4) o0[j] = f; else o1[j - 4] = f;
            }
            *(f4*)(out + i * 8) = o0;
            *(f4*)(out + i * 8 + 4) = o1;
        } else {
            __hip_bfloat16* out = (__hip_bfloat16*)outp;
            short8 o;
#pragma unroll
            for (int j = 0; j < 8; ++j) {
                float f = btof(v[j]) * ibn[c0 + j] + ibn[C + c0 + j] + btof(r[j]);
                o[j] = ftob(fmaxf(f, 0.f));
            }
            *(short8*)(out + i * 8) = o;
        }
    }
}

// ---------------- the cooperative mega-kernel ----------------
__global__ __launch_bounds__(256) void mega(MegaArgs a) {
    cg::grid_group grid = cg::this_grid();
    __shared__ float red[4096];   // 16 KB
    __shared__ float sred[512];   // 2 KB
    __shared__ float ibn[128];

    do_prologue(a);
    grid.sync();
    stage_stem(a);
    grid.sync();

    // enc1 block 0
    stage_conv<32, 32, 2, 27, false>(a.A, a.Wf + a.off_e1[0], a.m2, a.B,
        a.stats + 0 * 512, nullptr, nullptr, nullptr, a.nc2, a.nc2, red, sred, ibn);
    grid.sync();
    stage_conv<32, 32, 2, 27, true>(a.B, a.Wf + a.off_e1[1], a.m2, a.Cb,
        a.stats + 1 * 512, a.stats + 0 * 512, a.g_e1 + 0, a.b_e1 + 0,
        a.nc2, a.nc2, red, sred, ibn);
    grid.sync();
    stage_bnres<32, false>(a.Cb, a.A, a.stats + 1 * 512, a.g_e1 + 32, a.b_e1 + 32,
                           a.A, a.nc2, ibn);
    grid.sync();

    // enc1 block 1
    stage_conv<32, 32, 2, 27, false>(a.A, a.Wf + a.off_e1[2], a.m2, a.B,
        a.stats + 2 * 512, nullptr, nullptr, nullptr, a.nc2, a.nc2, red, sred, ibn);
    grid.sync();
    stage_conv<32, 32, 2, 27, true>(a.B, a.Wf + a.off_e1[3], a.m2, a.Cb,
        a.stats + 3 * 512, a.stats + 2 * 512, a.g_e1 + 64, a.b_e1 + 64,
        a.nc2, a.nc2, red, sred, ibn);
    grid.sync();
    stage_bnres<32, false>(a.Cb, a.A, a.stats + 3 * 512, a.g_e1 + 96, a.b_e1 + 96,
                           a.A, a.nc2, ibn);
    grid.sync();

    // conv2
    stage_conv<32, 64, 1, 27, false>(a.A, a.Wf + a.off_c2, a.m3, a.D,
        nullptr, nullptr, nullptr, nullptr, a.nc4, a.nc2, red, sred, ibn);
    grid.sync();

    // enc2 block 0
    stage_conv<64, 64, 1, 27, false>(a.D, a.Wf + a.off_e2[0], a.m4, a.E,
        a.stats + 4 * 512, nullptr, nullptr, nullptr, a.nc4, a.nc4, red, sred, ibn);
    grid.sync();
    stage_conv<64, 64, 1, 27, true>(a.E, a.Wf + a.off_e2[1], a.m4, a.Fb,
        a.stats + 5 * 512, a.stats + 4 * 512, a.g_e2 + 0, a.b_e2 + 0,
        a.nc4, a.nc4, red, sred, ibn);
    grid.sync();
    stage_bnres<64, false>(a.Fb, a.D, a.stats + 5 * 512, a.g_e2 + 64, a.b_e2 + 64,
                           a.D, a.nc4, ibn);
    grid.sync();

    // enc2 block 1
    stage_conv<64, 64, 1, 27, false>(a.D, a.Wf + a.off_e2[2], a.m4, a.E,
        a.stats + 6 * 512, nullptr, nullptr, nullptr, a.nc4, a.nc4, red, sred, ibn);
    grid.sync();
    stage_conv<64, 64, 1, 27, true>(a.E, a.Wf + a.off_e2[3], a.m4, a.Fb,
        a.stats + 7 * 512, a.stats + 6 * 512, a.g_e2 + 128, a.b_e2 + 128,
        a.nc4, a.nc4, red, sred, ibn);
    grid.sync();
    stage_bnres<64, true>(a.Fb, a.D, a.stats + 7 * 512, a.g_e2 + 192, a.b_e2 + 192,
                          a.outf, a.nc4, ibn);
}

// ---------------- fallback wrappers (r6-equivalent multi-kernel path) -------
__global__ __launch_bounds__(256) void k_prologue(MegaArgs a) { do_prologue(a); }
__global__ __launch_bounds__(256) void k_stem(MegaArgs a) { stage_stem(a); }

template <int CIN, int COUT, int MT, int K, bool BNF>
__global__ __launch_bounds__(256) void k_conv(
    const __hip_bfloat16* feat, const __hip_bfloat16* Wf, const int* in_map,
    __hip_bfloat16* out, float* stats, const float* ist, const float* ig,
    const float* ib, int n_out, int n_in) {
    __shared__ float red[4096];
    __shared__ float sred[512];
    __shared__ float ibn[128];
    stage_conv<CIN, COUT, MT, K, BNF>(feat, Wf, in_map, out, stats, ist, ig, ib,
                                      n_out, n_in, red, sred, ibn);
}

template <int C, bool F32OUT>
__global__ __launch_bounds__(256) void k_bnres(
    const __hip_bfloat16* y, const __hip_bfloat16* res, const float* st,
    const float* g, const float* b, void* out, int n) {
    __shared__ float ibn[128];
    stage_bnres<C, F32OUT>(y, res, st, g, b, out, n, ibn);
}

// ---------------------------------------------------------------------------
extern "C" void kernel_launch(void* const* d_in, const int* in_sizes, int n_in_cnt,
                              void* d_out, int out_size, void* d_ws, size_t ws_size,
                              hipStream_t stream) {
    const float* x_geo = (const float*)d_in[0];
    const float* x_col = (const float*)d_in[1];
    const float* w0    = (const float*)d_in[2];
    const float* w_e1  = (const float*)d_in[3];
    const float* g_e1  = (const float*)d_in[4];
    const float* b_e1  = (const float*)d_in[5];
    const float* w2    = (const float*)d_in[6];
    const float* w_e2  = (const float*)d_in[7];
    const float* g_e2  = (const float*)d_in[8];
    const float* b_e2  = (const float*)d_in[9];

    const int n_vox = in_sizes[0];
    const int nc2 = in_sizes[10] / 125;
    const int nc4 = in_sizes[14] / 27;
    (void)out_size; (void)ws_size; (void)n_in_cnt;

    char* p = (char*)d_ws;
    auto alloc = [&](size_t bytes) -> char* {
        char* r = p;
        p += (bytes + 255) & ~(size_t)255;
        return r;
    };
    float* stats = (float*)alloc(8 * 512 * sizeof(float));
    __hip_bfloat16* x0 = (__hip_bfloat16*)alloc((size_t)(n_vox + 1) * 4 * 2);
    __hip_bfloat16* A  = (__hip_bfloat16*)alloc((size_t)(nc2 + 1) * 32 * 2);
    __hip_bfloat16* B  = (__hip_bfloat16*)alloc((size_t)(nc2 + 1) * 32 * 2);
    __hip_bfloat16* Cb = (__hip_bfloat16*)alloc((size_t)(nc2 + 1) * 32 * 2);
    __hip_bfloat16* D  = (__hip_bfloat16*)alloc((size_t)(nc4 + 1) * 64 * 2);
    __hip_bfloat16* E  = (__hip_bfloat16*)alloc((size_t)(nc4 + 1) * 64 * 2);
    __hip_bfloat16* Fb = (__hip_bfloat16*)alloc((size_t)(nc4 + 1) * 64 * 2);

    const long long sz_stem = 16LL * 2 * 512;
    const long long sz_e1   = 28LL * 2 * 512;
    const long long sz_c2   = 28LL * 4 * 512;
    const long long sz_e2   = 56LL * 4 * 512;
    const long long wf_total = sz_stem + 4 * sz_e1 + sz_c2 + 4 * sz_e2;
    __hip_bfloat16* Wf = (__hip_bfloat16*)alloc((size_t)wf_total * 2);

    MegaArgs ma;
    long long cur = 0;
    auto seg = [&](int i, const float* W, int K, int CIN, int COUT, long long n) {
        ma.s[i].W = W; ma.s[i].K = K; ma.s[i].CIN = CIN; ma.s[i].COUT = COUT;
        ma.s[i].begin = cur; ma.s[i].end = cur + n; cur += n;
    };
    seg(0, w0, 125, 4, 32, sz_stem);
    for (int i = 0; i < 4; ++i)
        seg(1 + i, w_e1 + (size_t)i * 27 * 32 * 32, 27, 32, 32, sz_e1);
    seg(5, w2, 27, 32, 64, sz_c2);
    for (int i = 0; i < 4; ++i)
        seg(6 + i, w_e2 + (size_t)i * 27 * 64 * 64, 27, 64, 64, sz_e2);

    ma.off_stem = 0;
    cur = sz_stem;
    for (int i = 0; i < 4; ++i) { ma.off_e1[i] = cur; cur += sz_e1; }
    ma.off_c2 = cur; cur += sz_c2;
    for (int i = 0; i < 4; ++i) { ma.off_e2[i] = cur; cur += sz_e2; }

    ma.geo = x_geo; ma.col = x_col; ma.x0 = x0; ma.n_vox = n_vox;
    ma.stats = stats;
    ma.pads[0] = x0 + (size_t)n_vox * 4; ma.padn[0] = 4;
    ma.pads[1] = A + (size_t)nc2 * 32;   ma.padn[1] = 32;
    ma.pads[2] = B + (size_t)nc2 * 32;   ma.padn[2] = 32;
    ma.pads[3] = D + (size_t)nc4 * 64;   ma.padn[3] = 64;
    ma.pads[4] = E + (size_t)nc4 * 64;   ma.padn[4] = 64;
    ma.wf_total = wf_total;
    ma.pro_total = wf_total + n_vox + 4096 + (4 + 32 + 32 + 64 + 64);
    ma.Wf = Wf;
    ma.A = A; ma.B = B; ma.Cb = Cb; ma.D = D; ma.E = E; ma.Fb = Fb;
    ma.outf = (float*)d_out;
    ma.m1 = (const int*)d_in[10];
    ma.m2 = (const int*)d_in[12];
    ma.m3 = (const int*)d_in[14];
    ma.m4 = (const int*)d_in[16];
    ma.g_e1 = g_e1; ma.b_e1 = b_e1; ma.g_e2 = g_e2; ma.b_e2 = b_e2;
    ma.nc2 = nc2; ma.nc4 = nc4;

    // ---- try cooperative launch with occupancy-derived grid ----
    bool coop_done = false;
    int maxPerCU = 0;
    hipError_t qe = hipOccupancyMaxActiveBlocksPerMultiprocessor(
        &maxPerCU, (const void*)mega, 256, 0);
    int nCU = 0;
    int dev = 0;
    hipGetDevice(&dev);
    hipDeviceGetAttribute(&nCU, hipDeviceAttributeMultiprocessorCount, dev);
    if (qe == hipSuccess && maxPerCU > 0 && nCU > 0) {
        int grid = maxPerCU * nCU;
        void* kargs[] = { &ma };
        hipError_t le = hipLaunchCooperativeKernel((void*)mega, dim3(grid),
                                                   dim3(256), kargs, 0, stream);
        if (le == hipSuccess) coop_done = true;
        else (void)hipGetLastError();   // clear error state before fallback
    }
    if (coop_done) return;

    // ---- fallback: r6-equivalent multi-kernel sequence ----
    k_prologue<<<ceil_div((int)ma.pro_total, 256), 256, 0, stream>>>(ma);
    k_stem<<<ceil_div(nc2, 64), 256, 0, stream>>>(ma);

    k_conv<32, 32, 2, 27, false><<<ceil_div(nc2, 32), 256, 0, stream>>>(
        A, Wf + ma.off_e1[0], ma.m2, B, stats + 0 * 512,
        nullptr, nullptr, nullptr, nc2, nc2);
    k_conv<32, 32, 2, 27, true><<<ceil_div(nc2, 32), 256, 0, stream>>>(
        B, Wf + ma.off_e1[1], ma.m2, Cb, stats + 1 * 512,
        stats + 0 * 512, g_e1 + 0, b_e1 + 0, nc2, nc2);
    k_bnres<32, false><<<ceil_div(nc2 * 4, 256), 256, 0, stream>>>(
        Cb, A, stats + 1 * 512, g_e1 + 32, b_e1 + 32, A, nc2);

    k_conv<32, 32, 2, 27, false><<<ceil_div(nc2, 32), 256, 0, stream>>>(
        A, Wf + ma.off_e1[2], ma.m2, B, stats + 2 * 512,
        nullptr, nullptr, nullptr, nc2, nc2);
    k_conv<32, 32, 2, 27, true><<<ceil_div(nc2, 32), 256, 0, stream>>>(
        B, Wf + ma.off_e1[3], ma.m2, Cb, stats + 3 * 512,
        stats + 2 * 512, g_e1 + 64, b_e1 + 64, nc2, nc2);
    k_bnres<32, false><<<ceil_div(nc2 * 4, 256), 256, 0, stream>>>(
        Cb, A, stats + 3 * 512, g_e1 + 96, b_e1 + 96, A, nc2);

    k_conv<32, 64, 1, 27, false><<<ceil_div(nc4, 16), 256, 0, stream>>>(
        A, Wf + ma.off_c2, ma.m3, D, nullptr,
        nullptr, nullptr, nullptr, nc4, nc2);

    k_conv<64, 64, 1, 27, false><<<ceil_div(nc4, 16), 256, 0, stream>>>(
        D, Wf + ma.off_e2[0], ma.m4, E, stats + 4 * 512,
        nullptr, nullptr, nullptr, nc4, nc4);
    k_conv<64, 64, 1, 27, true><<<ceil_div(nc4, 16), 256, 0, stream>>>(
        E, Wf + ma.off_e2[1], ma.m4, Fb, stats + 5 * 512,
        stats + 4 * 512, g_e2 + 0, b_e2 + 0, nc4, nc4);
    k_bnres<64, false><<<ceil_div(nc4 * 8, 256), 256, 0, stream>>>(
        Fb, D, stats + 5 * 512, g_e2 + 64, b_e2 + 64, D, nc4);

    k_conv<64, 64, 1, 27, false><<<ceil_div(nc4, 16), 256, 0, stream>>>(
        D, Wf + ma.off_e2[2], ma.m4, E, stats + 6 * 512,
        nullptr, nullptr, nullptr, nc4, nc4);
    k_conv<64, 64, 1, 27, true><<<ceil_div(nc4, 16), 256, 0, stream>>>(
        E, Wf + ma.off_e2[3], ma.m4, Fb, stats + 7 * 512,
        stats + 6 * 512, g_e2 + 128, b_e2 + 128, nc4, nc4);
    k_bnres<64, true><<<ceil_div(nc4 * 8, 256), 256, 0, stream>>>(
        Fb, D, stats + 7 * 512, g_e2 + 192, b_e2 + 192, (float*)d_out, nc4);
}

// Round 9
// 322.093 us; speedup vs baseline: 1.9321x; 1.9321x over previous
//
#include <hip/hip_runtime.h>
#include <hip/hip_bf16.h>

// ---------------------------------------------------------------------------
// Sparse conv backbone, bf16 MFMA, round 9: multi-kernel (coop mega removed —
// r8 showed grid.sync costs >> launch gaps: 622 vs 342 us, MfmaUtil 1.4%).
// R9 vs r6: __launch_bounds__(256,4) caps conv VGPR at 128 (r8 measured 176
// -> 2 blocks/CU; gather-latency-bound convs need the 2x concurrency), and
// enc1 convs use MT=4 (R=64) to halve redundant B-fragment traffic.
// Math identical to r6/r8-mega (correctness-proven, absmax 0.125):
//   sparse_conv: out[j] = sum_k fpad[in_map[k][j]] @ W[k] (identity scatter)
//   MFMA 16x16x32 bf16; split-K over 4 waves (taps padded to 28, zero wts);
//   4-wave LDS reduce; BN stats in conv epilogue; bn_relu fused into the
//   consumer conv's gather.
// ---------------------------------------------------------------------------

typedef float f4 __attribute__((ext_vector_type(4)));
typedef short short8 __attribute__((ext_vector_type(8)));
typedef short short4v __attribute__((ext_vector_type(4)));

#define BN_EPS 1e-5f

static inline int ceil_div(int a, int b) { return (a + b - 1) / b; }
__device__ static inline int dceil(int a, int b) { return (a + b - 1) / b; }

static __device__ inline float btof(short s) {
    unsigned u = ((unsigned)(unsigned short)s) << 16;
    float f;
    __builtin_memcpy(&f, &u, 4);
    return f;
}
static __device__ inline short ftob(float f) {
    __hip_bfloat16 h = __float2bfloat16(f);
    short s;
    __builtin_memcpy(&s, &h, 2);
    return s;
}

struct Seg {
    const float* W;
    long long begin, end;
    int K, CIN, COUT;
};

struct ProArgs {
    Seg s[10];
    const float* geo;
    const float* col;
    __hip_bfloat16* x0;
    int n_vox;
    float* stats;
    __hip_bfloat16* pads[5];
    int padn[5];
    long long wf_total;
    long long pro_total;
    __hip_bfloat16* Wf;
    const int* m1;
    __hip_bfloat16* A;
    int nc2;
};

// ---------------- BN coefficient helper ----------------
template <int C>
__device__ inline void bn_coef(const float* st, const float* g, const float* b,
                               int c, int n, float& sc, float& sh) {
    float rn = 1.f / (float)n;
    float sum = st[c] + st[2 * C + c] + st[4 * C + c] + st[6 * C + c];
    float sq  = st[C + c] + st[3 * C + c] + st[5 * C + c] + st[7 * C + c];
    float mu = sum * rn;
    float inv = rsqrtf(sq * rn - mu * mu + BN_EPS);
    sc = inv * g[c];
    sh = b[c] - mu * sc;
}

// ---------------- prologue: pack weights + build x0 + zero stats/pads -------
__global__ __launch_bounds__(256) void k_prologue(ProArgs pa) {
    for (long long e = (long long)blockIdx.x * 256 + threadIdx.x; e < pa.pro_total;
         e += (long long)gridDim.x * 256) {
        if (e < pa.wf_total) {
            int si = 0;
#pragma unroll
            for (int i = 0; i < 10; ++i)
                if (e >= pa.s[i].end) si = i + 1;
            const Seg sg = pa.s[si];
            long long r = e - sg.begin;
            int j = (int)(r & 7);
            int lane = (int)((r >> 3) & 63);
            long long rest = r >> 9;
            int NT = sg.COUT >> 4;
            int ntile = (int)(rest % NT);
            int chunk = (int)(rest / NT);
            int kd = chunk * 32 + ((lane >> 4) << 3) + j;
            int koff = kd / sg.CIN;
            int ci = kd % sg.CIN;
            int n = ntile * 16 + (lane & 15);
            float v = (koff < sg.K) ? sg.W[((size_t)koff * sg.CIN + ci) * sg.COUT + n] : 0.f;
            pa.Wf[e] = __float2bfloat16(v);
            continue;
        }
        long long r = e - pa.wf_total;
        if (r < pa.n_vox) {
            int row = (int)r;
            pa.x0[row * 4 + 0] = __float2bfloat16(pa.geo[row]);
            pa.x0[row * 4 + 1] = __float2bfloat16(pa.col[row * 3 + 0]);
            pa.x0[row * 4 + 2] = __float2bfloat16(pa.col[row * 3 + 1]);
            pa.x0[row * 4 + 3] = __float2bfloat16(pa.col[row * 3 + 2]);
            continue;
        }
        r -= pa.n_vox;
        if (r < 4096) {
            pa.stats[r] = 0.f;
            continue;
        }
        r -= 4096;
#pragma unroll
        for (int i = 0; i < 5; ++i) {
            if (r < pa.padn[i]) {
                pa.pads[i][r] = __float2bfloat16(0.f);
                r = -1;
                break;
            }
            r -= pa.padn[i];
        }
    }
}

// ---------------- stem conv (CIN=4, COUT=32, K=125->128, relu) --------------
__global__ __launch_bounds__(256) void k_stem(ProArgs a) {
    const int t = threadIdx.x, w = t >> 6, lane = t & 63;
    const int quad = lane >> 4, ml = lane & 15;
    const int ntile = w & 1, mgroup = w >> 1;
    const int n_out = a.nc2, n_in = a.n_vox;
    const __hip_bfloat16* feat = a.x0;
    const __hip_bfloat16* Wf = a.Wf;   // stem at offset 0
    const int* in_map = a.m1;
    __hip_bfloat16* out = a.A;
    const int mb = blockIdx.x * 64 + mgroup * 32;
    const int m0 = mb + ml, m1 = mb + 16 + ml;
    const bool v0 = m0 < n_out, v1 = m1 < n_out;
    f4 acc0 = {0.f, 0.f, 0.f, 0.f};
    f4 acc1 = {0.f, 0.f, 0.f, 0.f};
#pragma unroll 2
    for (int chunk = 0; chunk < 16; ++chunk) {
        int k0 = chunk * 8 + quad * 2;
        int k1 = k0 + 1;
        int k0c = (k0 < 125) ? k0 : 0;   // weights zero for k>=125
        int k1c = (k1 < 125) ? k1 : 0;
        short8 b = *(const short8*)(Wf + ((size_t)(chunk * 2 + ntile) * 64 + lane) * 8);
        int ia = v0 ? in_map[(size_t)k0c * n_out + m0] : n_in;
        int ib = v0 ? in_map[(size_t)k1c * n_out + m0] : n_in;
        int ic = v1 ? in_map[(size_t)k0c * n_out + m1] : n_in;
        int id = v1 ? in_map[(size_t)k1c * n_out + m1] : n_in;
        short4v p0 = *(const short4v*)(feat + (size_t)ia * 4);
        short4v p1 = *(const short4v*)(feat + (size_t)ib * 4);
        short4v p2 = *(const short4v*)(feat + (size_t)ic * 4);
        short4v p3 = *(const short4v*)(feat + (size_t)id * 4);
        short8 a0, a1;
        a0[0] = p0[0]; a0[1] = p0[1]; a0[2] = p0[2]; a0[3] = p0[3];
        a0[4] = p1[0]; a0[5] = p1[1]; a0[6] = p1[2]; a0[7] = p1[3];
        a1[0] = p2[0]; a1[1] = p2[1]; a1[2] = p2[2]; a1[3] = p2[3];
        a1[4] = p3[0]; a1[5] = p3[1]; a1[6] = p3[2]; a1[7] = p3[3];
        acc0 = __builtin_amdgcn_mfma_f32_16x16x32_bf16(a0, b, acc0, 0, 0, 0);
        acc1 = __builtin_amdgcn_mfma_f32_16x16x32_bf16(a1, b, acc1, 0, 0, 0);
    }
    const int col = ntile * 16 + ml;
#pragma unroll
    for (int i = 0; i < 4; ++i) {
        int r0 = mb + quad * 4 + i;
        if (r0 < n_out)
            out[(size_t)r0 * 32 + col] = __float2bfloat16(fmaxf(acc0[i], 0.f));
        int r1 = mb + 16 + quad * 4 + i;
        if (r1 < n_out)
            out[(size_t)r1 * 32 + col] = __float2bfloat16(fmaxf(acc1[i], 0.f));
    }
}

// ---------------- split-K MFMA conv ----------------
// Block = 4 waves over R=MT*16 rows; wave w handles taps k=4*kk+w (padded,
// zero weights for k>=K). Optional fused input-BN+ReLU on gathered rows.
// __launch_bounds__(256,4): cap VGPR at 128 -> 4 blocks/CU (r8 measured 176
// VGPR -> 2 blocks/CU; convs are gather-latency-bound and need concurrency).
template <int CIN, int COUT, int MT, int K, bool BNF>
__global__ __launch_bounds__(256, 4) void k_conv(
    const __hip_bfloat16* __restrict__ feat,
    const __hip_bfloat16* __restrict__ Wf,
    const int* __restrict__ in_map,
    __hip_bfloat16* __restrict__ out,
    float* __restrict__ stats,
    const float* __restrict__ in_stats,
    const float* __restrict__ in_g,
    const float* __restrict__ in_b,
    int n_out, int n_in) {
    constexpr int NT = COUT / 16;
    constexpr int H = CIN / 32;
    constexpr int R = MT * 16;
    constexpr int KPW = (K + 3) / 4;
    const int t = threadIdx.x, w = t >> 6, lane = t & 63;
    const int quad = lane >> 4, ml = lane & 15;
    const int mb = blockIdx.x * R;

    __shared__ float red[4 * R * COUT];
    __shared__ float sred[2 * 256];
    __shared__ float ibn[2 * CIN];

    if constexpr (BNF) {
        if (t < CIN) {
            float sc, sh;
            bn_coef<CIN>(in_stats, in_g, in_b, t, n_in, sc, sh);
            ibn[t] = sc;
            ibn[CIN + t] = sh;
        }
        __syncthreads();
    }
    float scr[H][8], shr[H][8];
    if constexpr (BNF) {
#pragma unroll
        for (int h = 0; h < H; ++h)
#pragma unroll
            for (int j = 0; j < 8; ++j) {
                int ch = h * 32 + quad * 8 + j;
                scr[h][j] = ibn[ch];
                shr[h][j] = ibn[CIN + ch];
            }
    }

    f4 acc[MT * NT];
#pragma unroll
    for (int i = 0; i < MT * NT; ++i) acc[i] = (f4){0.f, 0.f, 0.f, 0.f};

#pragma unroll
    for (int kk = 0; kk < KPW; ++kk) {
        const int k = kk * 4 + w;
        const int krow = (k < K) ? k : 0;     // branchless; weights zero k>=K
        const int* mk = in_map + (size_t)krow * n_out;
        int idx[MT];
#pragma unroll
        for (int mi = 0; mi < MT; ++mi) {
            int m = mb + mi * 16 + ml;
            idx[mi] = (m < n_out) ? mk[m] : n_in;
        }
        short8 bfrag[H * NT];
#pragma unroll
        for (int h = 0; h < H; ++h)
#pragma unroll
            for (int nt = 0; nt < NT; ++nt)
                bfrag[h * NT + nt] = *(const short8*)(
                    Wf + (((size_t)(k * H + h) * NT + nt) * 64 + lane) * 8);
#pragma unroll
        for (int mi = 0; mi < MT; ++mi) {
            const __hip_bfloat16* fp = feat + (size_t)idx[mi] * CIN + quad * 8;
            const bool sent = (idx[mi] == n_in);
#pragma unroll
            for (int h = 0; h < H; ++h) {
                short8 av = *(const short8*)(fp + h * 32);
                if constexpr (BNF) {
#pragma unroll
                    for (int j = 0; j < 8; ++j) {
                        float f = btof(av[j]) * scr[h][j] + shr[h][j];
                        f = fmaxf(f, 0.f);
                        av[j] = sent ? (short)0 : ftob(f);
                    }
                }
#pragma unroll
                for (int nt = 0; nt < NT; ++nt)
                    acc[mi * NT + nt] = __builtin_amdgcn_mfma_f32_16x16x32_bf16(
                        av, bfrag[h * NT + nt], acc[mi * NT + nt], 0, 0, 0);
            }
        }
    }

#pragma unroll
    for (int mi = 0; mi < MT; ++mi)
#pragma unroll
        for (int nt = 0; nt < NT; ++nt)
#pragma unroll
            for (int i = 0; i < 4; ++i)
                red[((size_t)w * R + mi * 16 + quad * 4 + i) * COUT + nt * 16 + ml] =
                    acc[mi * NT + nt][i];
    __syncthreads();

    constexpr int E = (R * COUT) / 256;
    constexpr int RSTEP = 256 / COUT;
    const int col = t % COUT;
    const int rg = t / COUT;
    float s = 0.f, s2 = 0.f;
#pragma unroll
    for (int i = 0; i < E; ++i) {
        int r = rg + i * RSTEP;
        float v = red[(0 * R + r) * COUT + col] + red[(1 * R + r) * COUT + col] +
                  red[(2 * R + r) * COUT + col] + red[(3 * R + r) * COUT + col];
        s += v;
        s2 += v * v;
        int grow = mb + r;
        if (grow < n_out) out[(size_t)grow * COUT + col] = __float2bfloat16(v);
    }

    if (stats) {
        sred[t] = s;
        sred[256 + t] = s2;
        __syncthreads();
        if (t < 2 * COUT) {
            int c = t % COUT;
            int which = t / COUT;   // 0 = sum, 1 = sumsq
            float v = 0.f;
#pragma unroll
            for (int j = 0; j < RSTEP; ++j) v += sred[which * 256 + j * COUT + c];
            atomicAdd(&stats[((blockIdx.x & 3) * 2 + which) * COUT + c], v);
        }
    }
}

// ---------------- BN residual apply ----------------
template <int C, bool F32OUT>
__global__ __launch_bounds__(256) void k_bnres(
    const __hip_bfloat16* __restrict__ y, const __hip_bfloat16* __restrict__ res,
    const float* __restrict__ st, const float* __restrict__ g,
    const float* __restrict__ b, void* outp, int n) {
    __shared__ float ibn[2 * C];
    const int t = threadIdx.x;
    if (t < C) {
        float sc, sh;
        bn_coef<C>(st, g, b, t, n, sc, sh);
        ibn[t] = sc;
        ibn[C + t] = sh;
    }
    __syncthreads();
    long long tot = (long long)n * (C / 8);
    long long i = (long long)blockIdx.x * 256 + t;
    if (i >= tot) return;
    int c0 = (int)(i % (C / 8)) * 8;
    short8 v = *(const short8*)(y + i * 8);
    short8 r = *(const short8*)(res + i * 8);
    if constexpr (F32OUT) {
        float* out = (float*)outp;
        f4 o0, o1;
#pragma unroll
        for (int j = 0; j < 8; ++j) {
            float f = btof(v[j]) * ibn[c0 + j] + ibn[C + c0 + j] + btof(r[j]);
            f = fmaxf(f, 0.f);
            if (j < 4) o0[j] = f; else o1[j - 4] = f;
        }
        *(f4*)(out + i * 8) = o0;
        *(f4*)(out + i * 8 + 4) = o1;
    } else {
        __hip_bfloat16* out = (__hip_bfloat16*)outp;
        short8 o;
#pragma unroll
        for (int j = 0; j < 8; ++j) {
            float f = btof(v[j]) * ibn[c0 + j] + ibn[C + c0 + j] + btof(r[j]);
            o[j] = ftob(fmaxf(f, 0.f));
        }
        *(short8*)(out + i * 8) = o;
    }
}

// ---------------------------------------------------------------------------
extern "C" void kernel_launch(void* const* d_in, const int* in_sizes, int n_in_cnt,
                              void* d_out, int out_size, void* d_ws, size_t ws_size,
                              hipStream_t stream) {
    const float* x_geo = (const float*)d_in[0];
    const float* x_col = (const float*)d_in[1];
    const float* w0    = (const float*)d_in[2];
    const float* w_e1  = (const float*)d_in[3];
    const float* g_e1  = (const float*)d_in[4];
    const float* b_e1  = (const float*)d_in[5];
    const float* w2    = (const float*)d_in[6];
    const float* w_e2  = (const float*)d_in[7];
    const float* g_e2  = (const float*)d_in[8];
    const float* b_e2  = (const float*)d_in[9];
    const int* m1 = (const int*)d_in[10];
    const int* m2 = (const int*)d_in[12];
    const int* m3 = (const int*)d_in[14];
    const int* m4 = (const int*)d_in[16];

    const int n_vox = in_sizes[0];
    const int nc2 = in_sizes[10] / 125;
    const int nc4 = in_sizes[14] / 27;
    (void)out_size; (void)ws_size; (void)n_in_cnt;

    char* p = (char*)d_ws;
    auto alloc = [&](size_t bytes) -> char* {
        char* r = p;
        p += (bytes + 255) & ~(size_t)255;
        return r;
    };
    float* stats = (float*)alloc(8 * 512 * sizeof(float));
    __hip_bfloat16* x0 = (__hip_bfloat16*)alloc((size_t)(n_vox + 1) * 4 * 2);
    __hip_bfloat16* A  = (__hip_bfloat16*)alloc((size_t)(nc2 + 1) * 32 * 2);
    __hip_bfloat16* B  = (__hip_bfloat16*)alloc((size_t)(nc2 + 1) * 32 * 2);
    __hip_bfloat16* Cb = (__hip_bfloat16*)alloc((size_t)(nc2 + 1) * 32 * 2);
    __hip_bfloat16* D  = (__hip_bfloat16*)alloc((size_t)(nc4 + 1) * 64 * 2);
    __hip_bfloat16* E  = (__hip_bfloat16*)alloc((size_t)(nc4 + 1) * 64 * 2);
    __hip_bfloat16* Fb = (__hip_bfloat16*)alloc((size_t)(nc4 + 1) * 64 * 2);

    const long long sz_stem = 16LL * 2 * 512;
    const long long sz_e1   = 28LL * 2 * 512;
    const long long sz_c2   = 28LL * 4 * 512;
    const long long sz_e2   = 56LL * 4 * 512;
    const long long wf_total = sz_stem + 4 * sz_e1 + sz_c2 + 4 * sz_e2;
    __hip_bfloat16* Wf = (__hip_bfloat16*)alloc((size_t)wf_total * 2);

    ProArgs pa;
    long long cur = 0;
    auto seg = [&](int i, const float* W, int K, int CIN, int COUT, long long n) {
        pa.s[i].W = W; pa.s[i].K = K; pa.s[i].CIN = CIN; pa.s[i].COUT = COUT;
        pa.s[i].begin = cur; pa.s[i].end = cur + n; cur += n;
    };
    seg(0, w0, 125, 4, 32, sz_stem);
    for (int i = 0; i < 4; ++i)
        seg(1 + i, w_e1 + (size_t)i * 27 * 32 * 32, 27, 32, 32, sz_e1);
    seg(5, w2, 27, 32, 64, sz_c2);
    for (int i = 0; i < 4; ++i)
        seg(6 + i, w_e2 + (size_t)i * 27 * 64 * 64, 27, 64, 64, sz_e2);

    long long off_e1[4], off_e2[4];
    cur = sz_stem;
    for (int i = 0; i < 4; ++i) { off_e1[i] = cur; cur += sz_e1; }
    long long off_c2 = cur; cur += sz_c2;
    for (int i = 0; i < 4; ++i) { off_e2[i] = cur; cur += sz_e2; }

    pa.geo = x_geo; pa.col = x_col; pa.x0 = x0; pa.n_vox = n_vox;
    pa.stats = stats;
    pa.pads[0] = x0 + (size_t)n_vox * 4; pa.padn[0] = 4;
    pa.pads[1] = A + (size_t)nc2 * 32;   pa.padn[1] = 32;
    pa.pads[2] = B + (size_t)nc2 * 32;   pa.padn[2] = 32;
    pa.pads[3] = D + (size_t)nc4 * 64;   pa.padn[3] = 64;
    pa.pads[4] = E + (size_t)nc4 * 64;   pa.padn[4] = 64;
    pa.wf_total = wf_total;
    pa.pro_total = wf_total + n_vox + 4096 + (4 + 32 + 32 + 64 + 64);
    pa.Wf = Wf;
    pa.m1 = m1;
    pa.A = A;
    pa.nc2 = nc2;

    k_prologue<<<ceil_div((int)pa.pro_total, 256), 256, 0, stream>>>(pa);
    k_stem<<<ceil_div(nc2, 64), 256, 0, stream>>>(pa);

    // enc1: two BasicBlocks, 32ch on c2 (MT=4: R=64 rows/block, split-K 4)
    k_conv<32, 32, 4, 27, false><<<ceil_div(nc2, 64), 256, 0, stream>>>(
        A, Wf + off_e1[0], m2, B, stats + 0 * 512,
        nullptr, nullptr, nullptr, nc2, nc2);
    k_conv<32, 32, 4, 27, true><<<ceil_div(nc2, 64), 256, 0, stream>>>(
        B, Wf + off_e1[1], m2, Cb, stats + 1 * 512,
        stats + 0 * 512, g_e1 + 0, b_e1 + 0, nc2, nc2);
    k_bnres<32, false><<<ceil_div(nc2 * 4, 256), 256, 0, stream>>>(
        Cb, A, stats + 1 * 512, g_e1 + 32, b_e1 + 32, A, nc2);

    k_conv<32, 32, 4, 27, false><<<ceil_div(nc2, 64), 256, 0, stream>>>(
        A, Wf + off_e1[2], m2, B, stats + 2 * 512,
        nullptr, nullptr, nullptr, nc2, nc2);
    k_conv<32, 32, 4, 27, true><<<ceil_div(nc2, 64), 256, 0, stream>>>(
        B, Wf + off_e1[3], m2, Cb, stats + 3 * 512,
        stats + 2 * 512, g_e1 + 64, b_e1 + 64, nc2, nc2);
    k_bnres<32, false><<<ceil_div(nc2 * 4, 256), 256, 0, stream>>>(
        Cb, A, stats + 3 * 512, g_e1 + 96, b_e1 + 96, A, nc2);

    // conv2: 32ch@c2 -> 64ch@c4 (MT=1)
    k_conv<32, 64, 1, 27, false><<<ceil_div(nc4, 16), 256, 0, stream>>>(
        A, Wf + off_c2, m3, D, nullptr,
        nullptr, nullptr, nullptr, nc4, nc2);

    // enc2: two BasicBlocks, 64ch on c4 (MT=1)
    k_conv<64, 64, 1, 27, false><<<ceil_div(nc4, 16), 256, 0, stream>>>(
        D, Wf + off_e2[0], m4, E, stats + 4 * 512,
        nullptr, nullptr, nullptr, nc4, nc4);
    k_conv<64, 64, 1, 27, true><<<ceil_div(nc4, 16), 256, 0, stream>>>(
        E, Wf + off_e2[1], m4, Fb, stats + 5 * 512,
        stats + 4 * 512, g_e2 + 0, b_e2 + 0, nc4, nc4);
    k_bnres<64, false><<<ceil_div(nc4 * 8, 256), 256, 0, stream>>>(
        Fb, D, stats + 5 * 512, g_e2 + 64, b_e2 + 64, D, nc4);

    k_conv<64, 64, 1, 27, false><<<ceil_div(nc4, 16), 256, 0, stream>>>(
        D, Wf + off_e2[2], m4, E, stats + 6 * 512,
        nullptr, nullptr, nullptr, nc4, nc4);
    k_conv<64, 64, 1, 27, true><<<ceil_div(nc4, 16), 256, 0, stream>>>(
        E, Wf + off_e2[3], m4, Fb, stats + 7 * 512,
        stats + 6 * 512, g_e2 + 128, b_e2 + 128, nc4, nc4);
    k_bnres<64, true><<<ceil_div(nc4 * 8, 256), 256, 0, stream>>>(
        Fb, D, stats + 7 * 512, g_e2 + 192, b_e2 + 192, (float*)d_out, nc4);
}

// Round 10
// 321.616 us; speedup vs baseline: 1.9349x; 1.0015x over previous
//
#include <hip/hip_runtime.h>
#include <hip/hip_bf16.h>

// ---------------------------------------------------------------------------
// Sparse conv backbone, bf16 MFMA, round 10 = r9 + LDS bank-conflict fix.
// r8's mega profile showed SQ_LDS_BANK_CONFLICT = 1.49M: the split-K reduce
// stores red[w][row][col] with row stride COUT (=0 mod 32), so the 4 quads'
// rows collide on one bank (4-way, ~1.58x — m136). Row stride padded to
// COUT+1: store (4 rows, same col) and combine read (1 row, consecutive
// cols) both conflict-free.
// Everything else identical to r9 (322 us, absmax 0.109):
//   sparse_conv: out[j] = sum_k fpad[in_map[k][j]] @ W[k] (identity scatter)
//   MFMA 16x16x32 bf16; split-K over 4 waves (taps padded to 28, zero wts);
//   4-wave LDS reduce; BN stats in conv epilogue; bn_relu fused into the
//   consumer conv's gather; __launch_bounds__(256,4) -> 4 blocks/CU.
// ---------------------------------------------------------------------------

typedef float f4 __attribute__((ext_vector_type(4)));
typedef short short8 __attribute__((ext_vector_type(8)));
typedef short short4v __attribute__((ext_vector_type(4)));

#define BN_EPS 1e-5f

static inline int ceil_div(int a, int b) { return (a + b - 1) / b; }

static __device__ inline float btof(short s) {
    unsigned u = ((unsigned)(unsigned short)s) << 16;
    float f;
    __builtin_memcpy(&f, &u, 4);
    return f;
}
static __device__ inline short ftob(float f) {
    __hip_bfloat16 h = __float2bfloat16(f);
    short s;
    __builtin_memcpy(&s, &h, 2);
    return s;
}

struct Seg {
    const float* W;
    long long begin, end;
    int K, CIN, COUT;
};

struct ProArgs {
    Seg s[10];
    const float* geo;
    const float* col;
    __hip_bfloat16* x0;
    int n_vox;
    float* stats;
    __hip_bfloat16* pads[5];
    int padn[5];
    long long wf_total;
    long long pro_total;
    __hip_bfloat16* Wf;
    const int* m1;
    __hip_bfloat16* A;
    int nc2;
};

// ---------------- BN coefficient helper ----------------
template <int C>
__device__ inline void bn_coef(const float* st, const float* g, const float* b,
                               int c, int n, float& sc, float& sh) {
    float rn = 1.f / (float)n;
    float sum = st[c] + st[2 * C + c] + st[4 * C + c] + st[6 * C + c];
    float sq  = st[C + c] + st[3 * C + c] + st[5 * C + c] + st[7 * C + c];
    float mu = sum * rn;
    float inv = rsqrtf(sq * rn - mu * mu + BN_EPS);
    sc = inv * g[c];
    sh = b[c] - mu * sc;
}

// ---------------- prologue: pack weights + build x0 + zero stats/pads -------
__global__ __launch_bounds__(256) void k_prologue(ProArgs pa) {
    for (long long e = (long long)blockIdx.x * 256 + threadIdx.x; e < pa.pro_total;
         e += (long long)gridDim.x * 256) {
        if (e < pa.wf_total) {
            int si = 0;
#pragma unroll
            for (int i = 0; i < 10; ++i)
                if (e >= pa.s[i].end) si = i + 1;
            const Seg sg = pa.s[si];
            long long r = e - sg.begin;
            int j = (int)(r & 7);
            int lane = (int)((r >> 3) & 63);
            long long rest = r >> 9;
            int NT = sg.COUT >> 4;
            int ntile = (int)(rest % NT);
            int chunk = (int)(rest / NT);
            int kd = chunk * 32 + ((lane >> 4) << 3) + j;
            int koff = kd / sg.CIN;
            int ci = kd % sg.CIN;
            int n = ntile * 16 + (lane & 15);
            float v = (koff < sg.K) ? sg.W[((size_t)koff * sg.CIN + ci) * sg.COUT + n] : 0.f;
            pa.Wf[e] = __float2bfloat16(v);
            continue;
        }
        long long r = e - pa.wf_total;
        if (r < pa.n_vox) {
            int row = (int)r;
            pa.x0[row * 4 + 0] = __float2bfloat16(pa.geo[row]);
            pa.x0[row * 4 + 1] = __float2bfloat16(pa.col[row * 3 + 0]);
            pa.x0[row * 4 + 2] = __float2bfloat16(pa.col[row * 3 + 1]);
            pa.x0[row * 4 + 3] = __float2bfloat16(pa.col[row * 3 + 2]);
            continue;
        }
        r -= pa.n_vox;
        if (r < 4096) {
            pa.stats[r] = 0.f;
            continue;
        }
        r -= 4096;
#pragma unroll
        for (int i = 0; i < 5; ++i) {
            if (r < pa.padn[i]) {
                pa.pads[i][r] = __float2bfloat16(0.f);
                r = -1;
                break;
            }
            r -= pa.padn[i];
        }
    }
}

// ---------------- stem conv (CIN=4, COUT=32, K=125->128, relu) --------------
__global__ __launch_bounds__(256) void k_stem(ProArgs a) {
    const int t = threadIdx.x, w = t >> 6, lane = t & 63;
    const int quad = lane >> 4, ml = lane & 15;
    const int ntile = w & 1, mgroup = w >> 1;
    const int n_out = a.nc2, n_in = a.n_vox;
    const __hip_bfloat16* feat = a.x0;
    const __hip_bfloat16* Wf = a.Wf;   // stem at offset 0
    const int* in_map = a.m1;
    __hip_bfloat16* out = a.A;
    const int mb = blockIdx.x * 64 + mgroup * 32;
    const int m0 = mb + ml, m1 = mb + 16 + ml;
    const bool v0 = m0 < n_out, v1 = m1 < n_out;
    f4 acc0 = {0.f, 0.f, 0.f, 0.f};
    f4 acc1 = {0.f, 0.f, 0.f, 0.f};
#pragma unroll 2
    for (int chunk = 0; chunk < 16; ++chunk) {
        int k0 = chunk * 8 + quad * 2;
        int k1 = k0 + 1;
        int k0c = (k0 < 125) ? k0 : 0;   // weights zero for k>=125
        int k1c = (k1 < 125) ? k1 : 0;
        short8 b = *(const short8*)(Wf + ((size_t)(chunk * 2 + ntile) * 64 + lane) * 8);
        int ia = v0 ? in_map[(size_t)k0c * n_out + m0] : n_in;
        int ib = v0 ? in_map[(size_t)k1c * n_out + m0] : n_in;
        int ic = v1 ? in_map[(size_t)k0c * n_out + m1] : n_in;
        int id = v1 ? in_map[(size_t)k1c * n_out + m1] : n_in;
        short4v p0 = *(const short4v*)(feat + (size_t)ia * 4);
        short4v p1 = *(const short4v*)(feat + (size_t)ib * 4);
        short4v p2 = *(const short4v*)(feat + (size_t)ic * 4);
        short4v p3 = *(const short4v*)(feat + (size_t)id * 4);
        short8 a0, a1;
        a0[0] = p0[0]; a0[1] = p0[1]; a0[2] = p0[2]; a0[3] = p0[3];
        a0[4] = p1[0]; a0[5] = p1[1]; a0[6] = p1[2]; a0[7] = p1[3];
        a1[0] = p2[0]; a1[1] = p2[1]; a1[2] = p2[2]; a1[3] = p2[3];
        a1[4] = p3[0]; a1[5] = p3[1]; a1[6] = p3[2]; a1[7] = p3[3];
        acc0 = __builtin_amdgcn_mfma_f32_16x16x32_bf16(a0, b, acc0, 0, 0, 0);
        acc1 = __builtin_amdgcn_mfma_f32_16x16x32_bf16(a1, b, acc1, 0, 0, 0);
    }
    const int col = ntile * 16 + ml;
#pragma unroll
    for (int i = 0; i < 4; ++i) {
        int r0 = mb + quad * 4 + i;
        if (r0 < n_out)
            out[(size_t)r0 * 32 + col] = __float2bfloat16(fmaxf(acc0[i], 0.f));
        int r1 = mb + 16 + quad * 4 + i;
        if (r1 < n_out)
            out[(size_t)r1 * 32 + col] = __float2bfloat16(fmaxf(acc1[i], 0.f));
    }
}

// ---------------- split-K MFMA conv ----------------
// Block = 4 waves over R=MT*16 rows; wave w handles taps k=4*kk+w (padded,
// zero weights for k>=K). Optional fused input-BN+ReLU on gathered rows.
// LDS reduce buffer row stride = COUT+1 (conflict-free; see header).
template <int CIN, int COUT, int MT, int K, bool BNF>
__global__ __launch_bounds__(256, 4) void k_conv(
    const __hip_bfloat16* __restrict__ feat,
    const __hip_bfloat16* __restrict__ Wf,
    const int* __restrict__ in_map,
    __hip_bfloat16* __restrict__ out,
    float* __restrict__ stats,
    const float* __restrict__ in_stats,
    const float* __restrict__ in_g,
    const float* __restrict__ in_b,
    int n_out, int n_in) {
    constexpr int NT = COUT / 16;
    constexpr int H = CIN / 32;
    constexpr int R = MT * 16;
    constexpr int KPW = (K + 3) / 4;
    constexpr int SP = COUT + 1;     // padded LDS row stride
    const int t = threadIdx.x, w = t >> 6, lane = t & 63;
    const int quad = lane >> 4, ml = lane & 15;
    const int mb = blockIdx.x * R;

    __shared__ float red[4 * R * SP];
    __shared__ float sred[2 * 256];
    __shared__ float ibn[2 * CIN];

    if constexpr (BNF) {
        if (t < CIN) {
            float sc, sh;
            bn_coef<CIN>(in_stats, in_g, in_b, t, n_in, sc, sh);
            ibn[t] = sc;
            ibn[CIN + t] = sh;
        }
        __syncthreads();
    }
    float scr[H][8], shr[H][8];
    if constexpr (BNF) {
#pragma unroll
        for (int h = 0; h < H; ++h)
#pragma unroll
            for (int j = 0; j < 8; ++j) {
                int ch = h * 32 + quad * 8 + j;
                scr[h][j] = ibn[ch];
                shr[h][j] = ibn[CIN + ch];
            }
    }

    f4 acc[MT * NT];
#pragma unroll
    for (int i = 0; i < MT * NT; ++i) acc[i] = (f4){0.f, 0.f, 0.f, 0.f};

#pragma unroll
    for (int kk = 0; kk < KPW; ++kk) {
        const int k = kk * 4 + w;
        const int krow = (k < K) ? k : 0;     // branchless; weights zero k>=K
        const int* mk = in_map + (size_t)krow * n_out;
        int idx[MT];
#pragma unroll
        for (int mi = 0; mi < MT; ++mi) {
            int m = mb + mi * 16 + ml;
            idx[mi] = (m < n_out) ? mk[m] : n_in;
        }
        short8 bfrag[H * NT];
#pragma unroll
        for (int h = 0; h < H; ++h)
#pragma unroll
            for (int nt = 0; nt < NT; ++nt)
                bfrag[h * NT + nt] = *(const short8*)(
                    Wf + (((size_t)(k * H + h) * NT + nt) * 64 + lane) * 8);
#pragma unroll
        for (int mi = 0; mi < MT; ++mi) {
            const __hip_bfloat16* fp = feat + (size_t)idx[mi] * CIN + quad * 8;
            const bool sent = (idx[mi] == n_in);
#pragma unroll
            for (int h = 0; h < H; ++h) {
                short8 av = *(const short8*)(fp + h * 32);
                if constexpr (BNF) {
#pragma unroll
                    for (int j = 0; j < 8; ++j) {
                        float f = btof(av[j]) * scr[h][j] + shr[h][j];
                        f = fmaxf(f, 0.f);
                        av[j] = sent ? (short)0 : ftob(f);
                    }
                }
#pragma unroll
                for (int nt = 0; nt < NT; ++nt)
                    acc[mi * NT + nt] = __builtin_amdgcn_mfma_f32_16x16x32_bf16(
                        av, bfrag[h * NT + nt], acc[mi * NT + nt], 0, 0, 0);
            }
        }
    }

#pragma unroll
    for (int mi = 0; mi < MT; ++mi)
#pragma unroll
        for (int nt = 0; nt < NT; ++nt)
#pragma unroll
            for (int i = 0; i < 4; ++i)
                red[((size_t)w * R + mi * 16 + quad * 4 + i) * SP + nt * 16 + ml] =
                    acc[mi * NT + nt][i];
    __syncthreads();

    constexpr int E = (R * COUT) / 256;
    constexpr int RSTEP = 256 / COUT;
    const int col = t % COUT;
    const int rg = t / COUT;
    float s = 0.f, s2 = 0.f;
#pragma unroll
    for (int i = 0; i < E; ++i) {
        int r = rg + i * RSTEP;
        float v = red[(0 * R + r) * SP + col] + red[(1 * R + r) * SP + col] +
                  red[(2 * R + r) * SP + col] + red[(3 * R + r) * SP + col];
        s += v;
        s2 += v * v;
        int grow = mb + r;
        if (grow < n_out) out[(size_t)grow * COUT + col] = __float2bfloat16(v);
    }

    if (stats) {
        sred[t] = s;
        sred[256 + t] = s2;
        __syncthreads();
        if (t < 2 * COUT) {
            int c = t % COUT;
            int which = t / COUT;   // 0 = sum, 1 = sumsq
            float v = 0.f;
#pragma unroll
            for (int j = 0; j < RSTEP; ++j) v += sred[which * 256 + j * COUT + c];
            atomicAdd(&stats[((blockIdx.x & 3) * 2 + which) * COUT + c], v);
        }
    }
}

// ---------------- BN residual apply ----------------
template <int C, bool F32OUT>
__global__ __launch_bounds__(256) void k_bnres(
    const __hip_bfloat16* __restrict__ y, const __hip_bfloat16* __restrict__ res,
    const float* __restrict__ st, const float* __restrict__ g,
    const float* __restrict__ b, void* outp, int n) {
    __shared__ float ibn[2 * C];
    const int t = threadIdx.x;
    if (t < C) {
        float sc, sh;
        bn_coef<C>(st, g, b, t, n, sc, sh);
        ibn[t] = sc;
        ibn[C + t] = sh;
    }
    __syncthreads();
    long long tot = (long long)n * (C / 8);
    long long i = (long long)blockIdx.x * 256 + t;
    if (i >= tot) return;
    int c0 = (int)(i % (C / 8)) * 8;
    short8 v = *(const short8*)(y + i * 8);
    short8 r = *(const short8*)(res + i * 8);
    if constexpr (F32OUT) {
        float* out = (float*)outp;
        f4 o0, o1;
#pragma unroll
        for (int j = 0; j < 8; ++j) {
            float f = btof(v[j]) * ibn[c0 + j] + ibn[C + c0 + j] + btof(r[j]);
            f = fmaxf(f, 0.f);
            if (j < 4) o0[j] = f; else o1[j - 4] = f;
        }
        *(f4*)(out + i * 8) = o0;
        *(f4*)(out + i * 8 + 4) = o1;
    } else {
        __hip_bfloat16* out = (__hip_bfloat16*)outp;
        short8 o;
#pragma unroll
        for (int j = 0; j < 8; ++j) {
            float f = btof(v[j]) * ibn[c0 + j] + ibn[C + c0 + j] + btof(r[j]);
            o[j] = ftob(fmaxf(f, 0.f));
        }
        *(short8*)(out + i * 8) = o;
    }
}

// ---------------------------------------------------------------------------
extern "C" void kernel_launch(void* const* d_in, const int* in_sizes, int n_in_cnt,
                              void* d_out, int out_size, void* d_ws, size_t ws_size,
                              hipStream_t stream) {
    const float* x_geo = (const float*)d_in[0];
    const float* x_col = (const float*)d_in[1];
    const float* w0    = (const float*)d_in[2];
    const float* w_e1  = (const float*)d_in[3];
    const float* g_e1  = (const float*)d_in[4];
    const float* b_e1  = (const float*)d_in[5];
    const float* w2    = (const float*)d_in[6];
    const float* w_e2  = (const float*)d_in[7];
    const float* g_e2  = (const float*)d_in[8];
    const float* b_e2  = (const float*)d_in[9];
    const int* m1 = (const int*)d_in[10];
    const int* m2 = (const int*)d_in[12];
    const int* m3 = (const int*)d_in[14];
    const int* m4 = (const int*)d_in[16];

    const int n_vox = in_sizes[0];
    const int nc2 = in_sizes[10] / 125;
    const int nc4 = in_sizes[14] / 27;
    (void)out_size; (void)ws_size; (void)n_in_cnt;

    char* p = (char*)d_ws;
    auto alloc = [&](size_t bytes) -> char* {
        char* r = p;
        p += (bytes + 255) & ~(size_t)255;
        return r;
    };
    float* stats = (float*)alloc(8 * 512 * sizeof(float));
    __hip_bfloat16* x0 = (__hip_bfloat16*)alloc((size_t)(n_vox + 1) * 4 * 2);
    __hip_bfloat16* A  = (__hip_bfloat16*)alloc((size_t)(nc2 + 1) * 32 * 2);
    __hip_bfloat16* B  = (__hip_bfloat16*)alloc((size_t)(nc2 + 1) * 32 * 2);
    __hip_bfloat16* Cb = (__hip_bfloat16*)alloc((size_t)(nc2 + 1) * 32 * 2);
    __hip_bfloat16* D  = (__hip_bfloat16*)alloc((size_t)(nc4 + 1) * 64 * 2);
    __hip_bfloat16* E  = (__hip_bfloat16*)alloc((size_t)(nc4 + 1) * 64 * 2);
    __hip_bfloat16* Fb = (__hip_bfloat16*)alloc((size_t)(nc4 + 1) * 64 * 2);

    const long long sz_stem = 16LL * 2 * 512;
    const long long sz_e1   = 28LL * 2 * 512;
    const long long sz_c2   = 28LL * 4 * 512;
    const long long sz_e2   = 56LL * 4 * 512;
    const long long wf_total = sz_stem + 4 * sz_e1 + sz_c2 + 4 * sz_e2;
    __hip_bfloat16* Wf = (__hip_bfloat16*)alloc((size_t)wf_total * 2);

    ProArgs pa;
    long long cur = 0;
    auto seg = [&](int i, const float* W, int K, int CIN, int COUT, long long n) {
        pa.s[i].W = W; pa.s[i].K = K; pa.s[i].CIN = CIN; pa.s[i].COUT = COUT;
        pa.s[i].begin = cur; pa.s[i].end = cur + n; cur += n;
    };
    seg(0, w0, 125, 4, 32, sz_stem);
    for (int i = 0; i < 4; ++i)
        seg(1 + i, w_e1 + (size_t)i * 27 * 32 * 32, 27, 32, 32, sz_e1);
    seg(5, w2, 27, 32, 64, sz_c2);
    for (int i = 0; i < 4; ++i)
        seg(6 + i, w_e2 + (size_t)i * 27 * 64 * 64, 27, 64, 64, sz_e2);

    long long off_e1[4], off_e2[4];
    cur = sz_stem;
    for (int i = 0; i < 4; ++i) { off_e1[i] = cur; cur += sz_e1; }
    long long off_c2 = cur; cur += sz_c2;
    for (int i = 0; i < 4; ++i) { off_e2[i] = cur; cur += sz_e2; }

    pa.geo = x_geo; pa.col = x_col; pa.x0 = x0; pa.n_vox = n_vox;
    pa.stats = stats;
    pa.pads[0] = x0 + (size_t)n_vox * 4; pa.padn[0] = 4;
    pa.pads[1] = A + (size_t)nc2 * 32;   pa.padn[1] = 32;
    pa.pads[2] = B + (size_t)nc2 * 32;   pa.padn[2] = 32;
    pa.pads[3] = D + (size_t)nc4 * 64;   pa.padn[3] = 64;
    pa.pads[4] = E + (size_t)nc4 * 64;   pa.padn[4] = 64;
    pa.wf_total = wf_total;
    pa.pro_total = wf_total + n_vox + 4096 + (4 + 32 + 32 + 64 + 64);
    pa.Wf = Wf;
    pa.m1 = m1;
    pa.A = A;
    pa.nc2 = nc2;

    k_prologue<<<ceil_div((int)pa.pro_total, 256), 256, 0, stream>>>(pa);
    k_stem<<<ceil_div(nc2, 64), 256, 0, stream>>>(pa);

    // enc1: two BasicBlocks, 32ch on c2 (MT=4: R=64 rows/block, split-K 4)
    k_conv<32, 32, 4, 27, false><<<ceil_div(nc2, 64), 256, 0, stream>>>(
        A, Wf + off_e1[0], m2, B, stats + 0 * 512,
        nullptr, nullptr, nullptr, nc2, nc2);
    k_conv<32, 32, 4, 27, true><<<ceil_div(nc2, 64), 256, 0, stream>>>(
        B, Wf + off_e1[1], m2, Cb, stats + 1 * 512,
        stats + 0 * 512, g_e1 + 0, b_e1 + 0, nc2, nc2);
    k_bnres<32, false><<<ceil_div(nc2 * 4, 256), 256, 0, stream>>>(
        Cb, A, stats + 1 * 512, g_e1 + 32, b_e1 + 32, A, nc2);

    k_conv<32, 32, 4, 27, false><<<ceil_div(nc2, 64), 256, 0, stream>>>(
        A, Wf + off_e1[2], m2, B, stats + 2 * 512,
        nullptr, nullptr, nullptr, nc2, nc2);
    k_conv<32, 32, 4, 27, true><<<ceil_div(nc2, 64), 256, 0, stream>>>(
        B, Wf + off_e1[3], m2, Cb, stats + 3 * 512,
        stats + 2 * 512, g_e1 + 64, b_e1 + 64, nc2, nc2);
    k_bnres<32, false><<<ceil_div(nc2 * 4, 256), 256, 0, stream>>>(
        Cb, A, stats + 3 * 512, g_e1 + 96, b_e1 + 96, A, nc2);

    // conv2: 32ch@c2 -> 64ch@c4 (MT=1)
    k_conv<32, 64, 1, 27, false><<<ceil_div(nc4, 16), 256, 0, stream>>>(
        A, Wf + off_c2, m3, D, nullptr,
        nullptr, nullptr, nullptr, nc4, nc2);

    // enc2: two BasicBlocks, 64ch on c4 (MT=1)
    k_conv<64, 64, 1, 27, false><<<ceil_div(nc4, 16), 256, 0, stream>>>(
        D, Wf + off_e2[0], m4, E, stats + 4 * 512,
        nullptr, nullptr, nullptr, nc4, nc4);
    k_conv<64, 64, 1, 27, true><<<ceil_div(nc4, 16), 256, 0, stream>>>(
        E, Wf + off_e2[1], m4, Fb, stats + 5 * 512,
        stats + 4 * 512, g_e2 + 0, b_e2 + 0, nc4, nc4);
    k_bnres<64, false><<<ceil_div(nc4 * 8, 256), 256, 0, stream>>>(
        Fb, D, stats + 5 * 512, g_e2 + 64, b_e2 + 64, D, nc4);

    k_conv<64, 64, 1, 27, false><<<ceil_div(nc4, 16), 256, 0, stream>>>(
        D, Wf + off_e2[2], m4, E, stats + 6 * 512,
        nullptr, nullptr, nullptr, nc4, nc4);
    k_conv<64, 64, 1, 27, true><<<ceil_div(nc4, 16), 256, 0, stream>>>(
        E, Wf + off_e2[3], m4, Fb, stats + 7 * 512,
        stats + 6 * 512, g_e2 + 128, b_e2 + 128, nc4, nc4);
    k_bnres<64, true><<<ceil_div(nc4 * 8, 256), 256, 0, stream>>>(
        Fb, D, stats + 7 * 512, g_e2 + 192, b_e2 + 192, (float*)d_out, nc4);
}